// Round 1
// baseline (99.629 us; speedup 1.0000x reference)
//
#include <hip/hip_runtime.h>

#define BB 32
#define TT 12
#define NN 512
#define FF 64
#define HH 64
#define NBLK 64   // n-values per block; grid = BB * (NN/NBLK) = 256 blocks

// ---------------------------------------------------------------------------
// Kernel A: fused linear+DC-bin reduction.
// score-matrix S[i][j] += sum_{b,n in chunk} sq[b,i,n] * sk[b,j,n]
// where sq = x . rowsum(Wq) + sum(bq), sk likewise.
// ---------------------------------------------------------------------------
__global__ __launch_bounds__(256) void fft_sel_main(
    const float* __restrict__ x,   // [B,T,N,F]
    const float* __restrict__ Wq,  // [F,H]
    const float* __restrict__ bq,  // [H]
    const float* __restrict__ Wk,  // [F,H]
    const float* __restrict__ bk,  // [H]
    float* __restrict__ S)         // [T*T] accumulator (pre-zeroed)
{
    __shared__ float wq_s[FF];
    __shared__ float wk_s[FF];
    __shared__ float bsum[2];
    __shared__ float sq[TT][NBLK];
    __shared__ float sk[TT][NBLK];

    const int tid = threadIdx.x;

    // Per-block (redundant, L2-hit) weight column sums.
    if (tid < FF) {
        float a = 0.f;
        #pragma unroll
        for (int h = 0; h < HH; ++h) a += Wq[tid * HH + h];
        wq_s[tid] = a;
    } else if (tid < 2 * FF) {
        const int f = tid - FF;
        float a = 0.f;
        #pragma unroll
        for (int h = 0; h < HH; ++h) a += Wk[f * HH + h];
        wk_s[f] = a;
    } else if (tid == 2 * FF) {
        float a = 0.f;
        #pragma unroll
        for (int h = 0; h < HH; ++h) a += bq[h];
        bsum[0] = a;
    } else if (tid == 2 * FF + 1) {
        float a = 0.f;
        #pragma unroll
        for (int h = 0; h < HH; ++h) a += bk[h];
        bsum[1] = a;
    }
    __syncthreads();

    const int b  = blockIdx.x >> 3;            // NN/NBLK == 8 chunks per b
    const int n0 = (blockIdx.x & 7) * NBLK;
    const float bqs = bsum[0];
    const float bks = bsum[1];

    // 12*64 = 768 rows per block; 3 rows per thread. Each row = 64 contiguous
    // floats of cat_x; thread reads them as 16 x float4 (256B contiguous).
    for (int r = tid; r < TT * NBLK; r += 256) {
        const int t  = r >> 6;      // r / NBLK
        const int nl = r & 63;      // r % NBLK
        const float4* xp = (const float4*)(x +
            (((size_t)b * TT + t) * NN + (n0 + nl)) * FF);
        float dq = 0.f, dk = 0.f;
        #pragma unroll
        for (int u = 0; u < FF / 4; ++u) {
            const float4 v = xp[u];
            dq += v.x * wq_s[4*u]   + v.y * wq_s[4*u+1]
                + v.z * wq_s[4*u+2] + v.w * wq_s[4*u+3];
            dk += v.x * wk_s[4*u]   + v.y * wk_s[4*u+1]
                + v.z * wk_s[4*u+2] + v.w * wk_s[4*u+3];
        }
        sq[t][nl] = dq + bqs;
        sk[t][nl] = dk + bks;
    }
    __syncthreads();

    // 144 threads: (i,j) partial outer-product over the 64 local n's.
    if (tid < TT * TT) {
        const int i = tid / TT;
        const int j = tid % TT;
        float acc = 0.f;
        #pragma unroll
        for (int nl = 0; nl < NBLK; ++nl) acc += sq[i][nl] * sk[j][nl];
        atomicAdd(&S[tid], acc);
    }
}

// ---------------------------------------------------------------------------
// Kernel B: scale + per-row top-4 (stable: strict '>' keeps lowest index on
// ties, matching jax.lax.top_k). Writes scores [12,4] then indices [12,4]
// (as float — harness reads d_out as one flat float32 buffer).
// ---------------------------------------------------------------------------
__global__ void fft_sel_final(const float* __restrict__ S, float* __restrict__ out)
{
    const int i = threadIdx.x;
    if (i >= TT) return;
    const float scale = 1.0f / ((float)BB * (float)NN * (float)HH);
    float v[TT];
    bool used[TT];
    #pragma unroll
    for (int j = 0; j < TT; ++j) { v[j] = S[i * TT + j] * scale; used[j] = false; }
    #pragma unroll
    for (int s = 0; s < 4; ++s) {
        float best = -INFINITY;
        int bi = 0;
        for (int j = 0; j < TT; ++j) {
            if (!used[j] && v[j] > best) { best = v[j]; bi = j; }
        }
        used[bi] = true;
        out[i * 4 + s]            = best;        // scores
        out[TT * 4 + i * 4 + s]   = (float)bi;   // indices (as float)
    }
}

extern "C" void kernel_launch(void* const* d_in, const int* in_sizes, int n_in,
                              void* d_out, int out_size, void* d_ws, size_t ws_size,
                              hipStream_t stream) {
    const float* x  = (const float*)d_in[0];
    const float* Wq = (const float*)d_in[1];
    const float* bq = (const float*)d_in[2];
    const float* Wk = (const float*)d_in[3];
    const float* bk = (const float*)d_in[4];
    float* S = (float*)d_ws;

    hipMemsetAsync(d_ws, 0, TT * TT * sizeof(float), stream);
    fft_sel_main<<<BB * (NN / NBLK), 256, 0, stream>>>(x, Wq, bq, Wk, bk, S);
    fft_sel_final<<<1, 64, 0, stream>>>(S, (float*)d_out);
}